// Round 3
// baseline (677.444 us; speedup 1.0000x reference)
//
#include <hip/hip_runtime.h>
#include <stdint.h>

#define IN_F  4096
#define OUT_F 4096

typedef unsigned short u16;
typedef __attribute__((ext_vector_type(8))) short bf16x8;
typedef __attribute__((ext_vector_type(4))) float f32x4;

__device__ __forceinline__ u16 f2bf(float f) {
    union { float f; unsigned u; } c; c.f = f;
    unsigned u = c.u;
    return (u16)((u + 0x7FFFu + ((u >> 16) & 1u)) >> 16);
}
__device__ __forceinline__ float bf2f(u16 h) {
    union { unsigned u; float f; } c; c.u = ((unsigned)h) << 16;
    return c.f;
}
// pack two fp32 -> {hi=bf16(hi), lo=bf16(lo)} with round-half-up (+0x8000)
__device__ __forceinline__ unsigned pkbf(float lo, float hi) {
    union { float f; unsigned u; } a, b; a.f = lo; b.f = hi;
    return __builtin_amdgcn_perm(b.u + 0x8000u, a.u + 0x8000u, 0x07060302u);
}

// async global->LDS, 16B per lane. LDS dest is wave-uniform base + lane*16.
__device__ __forceinline__ void load_lds16(const void* g, void* l) {
    unsigned loff = (unsigned)(uintptr_t)l;
    loff = (unsigned)__builtin_amdgcn_readfirstlane((int)loff);
    __builtin_amdgcn_global_load_lds(
        (const __attribute__((address_space(1))) void*)(uintptr_t)g,
        (__attribute__((address_space(3))) void*)(uintptr_t)loff,
        16, 0, 0);
}

// ---------------------------------------------------------------------------
// Kernel 1: fused dequant + CSR outliers -> W bf16 [OUT][IN]
// (unchanged from R2 — passed, LDS-tiled transpose, both sides coalesced)
// ---------------------------------------------------------------------------
#define DQ_O 64
#define DQ_I 256

__global__ __launch_bounds__(256) void dequant_k(const int* __restrict__ qw,
                                                 const float* __restrict__ lut,
                                                 const int* __restrict__ rows,
                                                 const int* __restrict__ cols,
                                                 const float* __restrict__ vals,
                                                 u16* __restrict__ W) {
    __shared__ __align__(16) u16 sW[DQ_O * DQ_I];
    __shared__ u16 slut[DQ_O * 18];

    const int tid = threadIdx.x;
    const int o0 = blockIdx.y * DQ_O;
    const int i0 = blockIdx.x * DQ_I;
    const int p0 = i0 >> 3;

    {
        const int idx = tid * 4;
        const float4 v = *(const float4*)(lut + (size_t)o0 * 16 + idx);
        u16* d = slut + (idx >> 4) * 18 + (idx & 15);
        d[0] = f2bf(v.x); d[1] = f2bf(v.y); d[2] = f2bf(v.z); d[3] = f2bf(v.w);
    }
    __syncthreads();

    const int o_l = tid & 63;
    const int swz = o_l & 31;
#pragma unroll
    for (int it = 0; it < 8; ++it) {
        const int p = (tid >> 6) + it * 4;
        const unsigned w = (unsigned)qw[(size_t)(p0 + p) * OUT_F + (o0 + o_l)];
        union { u16 h[8]; uint4 v; } u;
#pragma unroll
        for (int j = 0; j < 8; ++j)
            u.h[j] = slut[o_l * 18 + ((w >> (4 * j)) & 15u)];
        *(uint4*)(sW + o_l * DQ_I + ((p ^ swz) << 3)) = u.v;
    }
    __syncthreads();

    if (tid < DQ_O) {
        const int s = rows[o0 + tid], e = rows[o0 + tid + 1];
        for (int k = s; k < e; ++k) {
            const unsigned j = (unsigned)(cols[k] - i0);
            if (j < DQ_I) {
                u16* p16 = sW + tid * DQ_I + (((j >> 3) ^ swz) << 3) + (j & 7);
                *p16 = f2bf(bf2f(*p16) + vals[k]);
            }
        }
    }
    __syncthreads();

    const int ch = tid & 31;
#pragma unroll
    for (int it = 0; it < 8; ++it) {
        const int r = (tid >> 5) + it * 8;
        *(uint4*)(W + (size_t)(o0 + r) * IN_F + i0 + ch * 8) =
            *(const uint4*)(sW + r * DQ_I + ((ch ^ (r & 31)) << 3));
    }
}

// ---------------------------------------------------------------------------
// Kernel 2: GEMM  y[M][N] = X[M][K](fp32) * W[N][K]^T(bf16) + bias -> fp32
// m97 structure, but A staged as fp32 directly from x (cvtx fused away).
// A LDS rows are rotation-swizzled (col' = (k + 4*(row&7)) % 32) so fragment
// ds_read_b128 windows tile all 32 banks (8 dwords/bank minimum).
// fp32->bf16 conversion at fragment read: +0x8000 round-half-up, v_perm pack.
// ---------------------------------------------------------------------------
#define BM 128
#define BN 128
#define BK 32
#define GK 4096

__global__ __launch_bounds__(256) void gemm_k(const float* __restrict__ X,
                                              const u16* __restrict__ B,
                                              const float* __restrict__ bias,
                                              float* __restrict__ C,
                                              int M, int N) {
    __shared__ __align__(16) float sA[BM * BK];   // 16 KB, rotated rows
    __shared__ __align__(16) u16   sB[BN * BK];   // 8 KB

    const int tid  = threadIdx.x;
    const int wave = tid >> 6;
    const int lane = tid & 63;
    const int bm = blockIdx.y * BM;
    const int bn = blockIdx.x * BN;

    // ---- A staging (fp32, rotated): 4 insts/wave, 8 rows x 32 floats each.
    // lane -> row_rel = lane>>3, LDS col' = (lane&7)*4; rot = (row&7)*4 = (lane>>3)*4
    // fetched k = (col' - rot) & 31
    const int ar = lane >> 3;
    const int ac = lane & 7;
    const int akoff = (((ac - ar) & 7) << 2);
    const float* gA = X + (size_t)(bm + wave * 8 + ar) * GK + akoff;
    float* laA = sA + (wave * 8) * BK;

    // ---- B staging (bf16): 2 insts/wave, 16 rows x 32 u16 each
    const int srow = wave * 16 + (lane >> 2);
    const int scol = (lane & 3) * 8;
    const u16* gb0 = B + (size_t)(bn + srow) * GK + scol;
    const u16* gb1 = gb0 + (size_t)64 * GK;
    u16* lb0 = sB + wave * 512;
    u16* lb1 = lb0 + 2048;

    // ---- fragment indices
    const int frow = lane & 15;
    const int q    = lane >> 4;            // k-quad: k = q*8 + j
    const int fkB  = q * 8;                // B frag k offset (u16, unswizzled)
    const int s0   = ((q * 8) + ((frow & 7) << 2)) & 31;  // A frag float col
    const int s1   = (s0 + 4) & 31;

    const int wm = (wave >> 1) * 64;
    const int wn = (wave & 1) * 64;

    f32x4 acc[4][4] = {};

    for (int k0 = 0; k0 < GK; k0 += BK) {
        __syncthreads();
#pragma unroll
        for (int it = 0; it < 4; ++it)
            load_lds16(gA + k0 + (size_t)it * 32 * GK, laA + it * 32 * BK);
        load_lds16(gb0 + k0, lb0);
        load_lds16(gb1 + k0, lb1);
        __syncthreads();

        bf16x8 bfr[4];
        union { bf16x8 v; unsigned u[4]; } af[4];
#pragma unroll
        for (int t = 0; t < 4; ++t) {
            const float* pa = sA + (wm + t * 16 + frow) * BK;
            const float4 f0 = *(const float4*)(pa + s0);
            const float4 f1 = *(const float4*)(pa + s1);
            af[t].u[0] = pkbf(f0.x, f0.y);
            af[t].u[1] = pkbf(f0.z, f0.w);
            af[t].u[2] = pkbf(f1.x, f1.y);
            af[t].u[3] = pkbf(f1.z, f1.w);
            bfr[t] = *(const bf16x8*)(sB + (wn + t * 16 + frow) * BK + fkB);
        }
#pragma unroll
        for (int i = 0; i < 4; ++i)
#pragma unroll
            for (int j = 0; j < 4; ++j)
                acc[i][j] = __builtin_amdgcn_mfma_f32_16x16x32_bf16(
                    af[i].v, bfr[j], acc[i][j], 0, 0, 0);
    }

    const int cm = bm + wm;
    const int cn = bn + wn;
#pragma unroll
    for (int j = 0; j < 4; ++j) {
        const int col = cn + j * 16 + (lane & 15);
        const float bv = bias[col];
#pragma unroll
        for (int i = 0; i < 4; ++i) {
            const int r0 = cm + i * 16 + (lane >> 4) * 4;
#pragma unroll
            for (int r = 0; r < 4; ++r)
                C[(size_t)(r0 + r) * N + col] = acc[i][j][r] + bv;
        }
    }
}

// ---------------------------------------------------------------------------
extern "C" void kernel_launch(void* const* d_in, const int* in_sizes, int n_in,
                              void* d_out, int out_size, void* d_ws, size_t ws_size,
                              hipStream_t stream) {
    (void)n_in; (void)out_size; (void)ws_size;
    const float* x     = (const float*)d_in[0];
    const float* lut   = (const float*)d_in[1];
    const float* bias  = (const float*)d_in[2];
    const float* ovals = (const float*)d_in[3];
    const int*   qw    = (const int*)d_in[4];
    const int*   orows = (const int*)d_in[5];
    const int*   ocols = (const int*)d_in[6];
    float* y = (float*)d_out;

    const int M = in_sizes[0] / IN_F;   // 8192

    u16* W = (u16*)d_ws;                // 32 MB

    dim3 dq_grid(IN_F / DQ_I, OUT_F / DQ_O);
    dequant_k<<<dq_grid, 256, 0, stream>>>(qw, lut, orows, ocols, ovals, W);
    dim3 grid(OUT_F / BN, M / BM);
    gemm_k<<<grid, 256, 0, stream>>>(x, W, bias, y, M, OUT_F);
}